// Round 3
// baseline (175.750 us; speedup 1.0000x reference)
//
#include <hip/hip_runtime.h>

#define B 4
#define C 256
#define CI 128
#define NPIX 3136      // 56*56 = 49 * 64
#define KS 7           // split-K for xxt: 7 chunks of 448
#define BN_EPS_F 1e-5f
#define INVN (1.0f / 3136.0f)

typedef float f4 __attribute__((ext_vector_type(4)));
typedef float f32x4 __attribute__((ext_vector_type(4)));
typedef short short8 __attribute__((ext_vector_type(8)));
typedef short short4v __attribute__((ext_vector_type(4)));

__device__ inline short f2bf(float f) {
    unsigned u = __builtin_bit_cast(unsigned, f);
    unsigned r = (u + 0x7FFFu + ((u >> 16) & 1u)) >> 16;
    return (short)r;
}

// ---- prep: xbf[b][c][n]=bf16(x), xT[b][n][c]=bf16(x), s[b][c]=rowsum (atomic) ----
// grid (49, 4, B), block 256
__global__ __launch_bounds__(256) void prep_kernel(const float* __restrict__ x,
                                                   short* __restrict__ xbf,
                                                   short* __restrict__ xT,
                                                   float* __restrict__ s) {
    int b = blockIdx.z, c0 = blockIdx.y * 64, n0 = blockIdx.x * 64;
    __shared__ short lds[64][65];   // [n_local][c_local]
    int t = threadIdx.x;
    int nf = (t & 15) * 4;
    int cr = t >> 4;
    float psum[4];
#pragma unroll
    for (int it = 0; it < 4; ++it) {
        int c = cr + 16 * it;
        f4 v = *(const f4*)&x[((size_t)(b * C + c0 + c)) * NPIX + n0 + nf];
        short4v s4;
        float ps = 0.f;
#pragma unroll
        for (int i = 0; i < 4; ++i) { s4[i] = f2bf(v[i]); ps += v[i]; }
        psum[it] = ps;
        *(short4v*)&xbf[((size_t)(b * C + c0 + c)) * NPIX + n0 + nf] = s4;
#pragma unroll
        for (int i = 0; i < 4; ++i) lds[nf + i][c] = s4[i];
    }
    // reduce within each 16-lane group (same cr), one atomic per (c, block)
#pragma unroll
    for (int it = 0; it < 4; ++it) {
        float ps = psum[it];
#pragma unroll
        for (int m = 8; m >= 1; m >>= 1) ps += __shfl_xor(ps, m, 64);
        if ((t & 15) == 0) atomicAdd(&s[b * C + c0 + cr + 16 * it], ps);
    }
    __syncthreads();
#pragma unroll
    for (int it = 0; it < 4; ++it) {
        int n = cr + 16 * it;
        short4v s4;
#pragma unroll
        for (int i = 0; i < 4; ++i) s4[i] = lds[n][nf + i];
        *(short4v*)&xT[((size_t)b * NPIX + n0 + n) * C + c0 + nf] = s4;
    }
}

// ---- lr: L = diag(inv) wrec Wg (256x256), R = Wphi^T Wtheta (256x256),
//          p = inv.*(wrec bg), t = Wtheta^T bphi, wt = Wphi^T btheta,
//          swt[b] = s[b].wt, consts[0] = bphi.btheta
// grid 33 blocks: 0-15 L tiles, 16-31 R tiles, 32 vectors.
__global__ __launch_bounds__(256) void lr_kernel(const float* __restrict__ wrec,
                                                 const float* __restrict__ wg,
                                                 const float* __restrict__ wphi,
                                                 const float* __restrict__ wtheta,
                                                 const float* __restrict__ gamma,
                                                 const float* __restrict__ var,
                                                 const float* __restrict__ bg,
                                                 const float* __restrict__ bphi,
                                                 const float* __restrict__ btheta,
                                                 const float* __restrict__ s,
                                                 float* __restrict__ L,
                                                 float* __restrict__ R,
                                                 float* __restrict__ p,
                                                 float* __restrict__ tg,
                                                 float* __restrict__ wt,
                                                 float* __restrict__ swt,
                                                 float* __restrict__ consts) {
    __shared__ float wl[64][68];
    __shared__ float xl[64][68];
    __shared__ float wtl[C];
    int bx = blockIdx.x;
    int t = threadIdx.x;
    if (bx == 32) {
        float acc_t = 0.f, acc_w = 0.f, accp = 0.f;
        for (int j = 0; j < CI; ++j) {
            float bp = bphi[j], bt = btheta[j];
            acc_t += wtheta[j * C + t] * bp;
            acc_w += wphi[j * C + t] * bt;
            accp  += wrec[t * CI + j] * bg[j];
        }
        tg[t] = acc_t;
        wt[t] = acc_w;
        wtl[t] = acc_w;
        p[t] = gamma[t] * rsqrtf(var[t] + BN_EPS_F) * accp;
        __syncthreads();
        if (t < B) {
            float a = 0.f;
            for (int c = 0; c < C; ++c) a += s[t * C + c] * wtl[c];
            swt[t] = a;
        }
        if (t == 4) {
            float a = 0.f;
            for (int j = 0; j < CI; ++j) a += bphi[j] * btheta[j];
            consts[0] = a;
        }
        return;
    }
    bool isL = bx < 16;
    int bi = isL ? bx : bx - 16;
    int r0 = (bi >> 2) * 64, cc0 = (bi & 3) * 64;
    int tx = t & 15, ty = t >> 4;
    float acc[4][4] = {};
    for (int k0 = 0; k0 < CI; k0 += 64) {
        __syncthreads();
        if (isL) {
#pragma unroll
            for (int l = 0; l < 4; ++l) {
                int idx = t + l * 256;
                int r = idx >> 4, c4 = (idx & 15) << 2;
                *(f4*)&wl[r][c4] = *(const f4*)&wrec[(r0 + r) * CI + k0 + c4];
                *(f4*)&xl[r][c4] = *(const f4*)&wg[(size_t)(k0 + r) * C + cc0 + c4];
            }
        } else {
#pragma unroll
            for (int l = 0; l < 4; ++l) {
                int idx = t + l * 256;
                int jl = idx >> 4, cf4 = (idx & 15) << 2;
                f4 v = *(const f4*)&wphi[(size_t)(k0 + jl) * C + r0 + cf4];
#pragma unroll
                for (int i = 0; i < 4; ++i) wl[cf4 + i][jl] = v[i];
                *(f4*)&xl[jl][cf4] = *(const f4*)&wtheta[(size_t)(k0 + jl) * C + cc0 + cf4];
            }
        }
        __syncthreads();
        for (int kk = 0; kk < 64; kk += 4) {
            f4 a[4], bb[4];
#pragma unroll
            for (int i = 0; i < 4; ++i) a[i] = *(const f4*)&wl[ty + 16 * i][kk];
#pragma unroll
            for (int q = 0; q < 4; ++q) bb[q] = *(const f4*)&xl[kk + q][tx * 4];
#pragma unroll
            for (int q = 0; q < 4; ++q)
#pragma unroll
                for (int i = 0; i < 4; ++i)
#pragma unroll
                    for (int j = 0; j < 4; ++j)
                        acc[i][j] += a[i][q] * bb[q][j];
        }
    }
#pragma unroll
    for (int i = 0; i < 4; ++i) {
        int r = r0 + ty + 16 * i;
        float scale = isL ? gamma[r] * rsqrtf(var[r] + BN_EPS_F) : 1.0f;
        float* dst = isL ? L : R;
#pragma unroll
        for (int j = 0; j < 4; ++j)
            dst[r * C + cc0 + tx * 4 + j] = scale * acc[i][j];
    }
}

// ---- Gpart[ks][b] = x_chunk x_chunk^T (bf16 MFMA) ----
__global__ __launch_bounds__(256) void xxt_mfma(const short* __restrict__ xbf,
                                                float* __restrict__ Gp) {
    int z = blockIdx.z;
    int b = z / KS, ks = z % KS;
    int tid = threadIdx.x, lane = tid & 63, wid = tid >> 6;
    int ibase = blockIdx.y * 128 + (wid >> 1) * 64;
    int jbase = blockIdx.x * 128 + (wid & 1) * 64;
    int lm = lane & 15, lk = (lane >> 4) * 8;
    const short* A0 = xbf + ((size_t)(b * C) + ibase + lm) * NPIX + lk;
    const short* B0 = xbf + ((size_t)(b * C) + jbase + lm) * NPIX + lk;
    f32x4 acc[4][4] = {};
    int kend = ks * 448 + 448;
    for (int k = ks * 448; k < kend; k += 32) {
        short8 a[4], bv[4];
#pragma unroll
        for (int mi = 0; mi < 4; ++mi) a[mi] = *(const short8*)(A0 + (size_t)mi * 16 * NPIX + k);
#pragma unroll
        for (int nj = 0; nj < 4; ++nj) bv[nj] = *(const short8*)(B0 + (size_t)nj * 16 * NPIX + k);
#pragma unroll
        for (int mi = 0; mi < 4; ++mi)
#pragma unroll
            for (int nj = 0; nj < 4; ++nj)
                acc[mi][nj] = __builtin_amdgcn_mfma_f32_16x16x32_bf16(a[mi], bv[nj], acc[mi][nj], 0, 0, 0);
    }
    float* outp = Gp + ((size_t)(ks * B + b)) * C * C;
    int r0 = (lane >> 4) * 4;
#pragma unroll
    for (int mi = 0; mi < 4; ++mi)
#pragma unroll
        for (int r = 0; r < 4; ++r)
#pragma unroll
            for (int nj = 0; nj < 4; ++nj)
                outp[(ibase + mi * 16 + r0 + r) * C + jbase + nj * 16 + lm] = acc[mi][nj][r];
}

// ---- h: H[b] = L * (sum_ks Gp[ks][b]);  Ls[b] = L s[b] (jt==0 blocks) ----
// grid (4 jt, 4 it, B), block 256
__global__ __launch_bounds__(256) void h_kernel(const float* __restrict__ L,
                                                const float* __restrict__ Gp,
                                                const float* __restrict__ s,
                                                float* __restrict__ H,
                                                float* __restrict__ Ls) {
    int jt = blockIdx.x, it = blockIdx.y, b = blockIdx.z;
    int i0 = it * 64, j0 = jt * 64;
    __shared__ float wl[64][68];
    __shared__ float xl[64][68];
    __shared__ float sl[C];
    int t = threadIdx.x, tx = t & 15, ty = t >> 4;
    sl[t] = s[b * C + t];
    float acc[4][4] = {};
    float lsacc[4] = {};
    for (int k0 = 0; k0 < C; k0 += 64) {
        __syncthreads();
#pragma unroll
        for (int l = 0; l < 4; ++l) {
            int idx = t + l * 256;
            int r = idx >> 4, c4 = (idx & 15) << 2;
            *(f4*)&wl[r][c4] = *(const f4*)&L[(i0 + r) * C + k0 + c4];
            f4 g = *(const f4*)&Gp[(size_t)b * C * C + (k0 + r) * C + j0 + c4];
#pragma unroll
            for (int ks = 1; ks < KS; ++ks)
                g += *(const f4*)&Gp[(size_t)ks * (B * C * C) + (size_t)b * C * C + (k0 + r) * C + j0 + c4];
            *(f4*)&xl[r][c4] = g;
        }
        __syncthreads();
        for (int kk = 0; kk < 64; kk += 4) {
            f4 a[4], bb[4];
#pragma unroll
            for (int i = 0; i < 4; ++i) a[i] = *(const f4*)&wl[ty + 16 * i][kk];
#pragma unroll
            for (int q = 0; q < 4; ++q) bb[q] = *(const f4*)&xl[kk + q][tx * 4];
#pragma unroll
            for (int q = 0; q < 4; ++q) {
#pragma unroll
                for (int i = 0; i < 4; ++i) {
                    lsacc[i] += ((q == 0) ? a[i][0] * sl[k0 + kk] : 0.f);
#pragma unroll
                    for (int j = 0; j < 4; ++j)
                        acc[i][j] += a[i][q] * bb[q][j];
                }
            }
#pragma unroll
            for (int i = 0; i < 4; ++i) {
                lsacc[i] += a[i][1] * sl[k0 + kk + 1] + a[i][2] * sl[k0 + kk + 2] + a[i][3] * sl[k0 + kk + 3];
            }
        }
    }
    float* Hb = H + (size_t)b * C * C;
#pragma unroll
    for (int i = 0; i < 4; ++i)
#pragma unroll
        for (int j = 0; j < 4; ++j)
            Hb[(i0 + ty + 16 * i) * C + j0 + tx * 4 + j] = acc[i][j];
    if (jt == 0 && tx == 0) {
#pragma unroll
        for (int i = 0; i < 4; ++i) Ls[b * C + i0 + ty + 16 * i] = lsacc[i];
    }
}

// ---- w5: W5bf[b] = bf16((1/N) H R + p*((1/N)s^T R + t)^T + (1/N)(Ls) t^T)
//         bias5[b][o] (jt==0): (1/N)H wt + (1/N)swt p + cpt((1/N)Ls + p) + BN terms
// grid (4 jt, 4 it, B), block 256
__global__ __launch_bounds__(256) void w5_kernel(const float* __restrict__ H,
                                                 const float* __restrict__ R,
                                                 const float* __restrict__ s,
                                                 const float* __restrict__ wt,
                                                 const float* __restrict__ tg,
                                                 const float* __restrict__ p,
                                                 const float* __restrict__ Ls,
                                                 const float* __restrict__ swt,
                                                 const float* __restrict__ consts,
                                                 const float* __restrict__ gamma,
                                                 const float* __restrict__ var,
                                                 const float* __restrict__ beta,
                                                 const float* __restrict__ mean,
                                                 const float* __restrict__ brec,
                                                 short* __restrict__ W5bf,
                                                 float* __restrict__ bias5) {
    int jt = blockIdx.x, it = blockIdx.y, b = blockIdx.z;
    int o0 = it * 64, c0 = jt * 64;
    __shared__ float wl[64][68];
    __shared__ float xl[64][68];
    __shared__ float sl[C];
    __shared__ float wtl[C];
    int t = threadIdx.x, tx = t & 15, ty = t >> 4;
    sl[t] = s[b * C + t];
    wtl[t] = wt[t];
    float acc[4][4] = {};
    float qacc[4] = {};
    float hwacc[4] = {};
    const float* Hb = H + (size_t)b * C * C;
    for (int k0 = 0; k0 < C; k0 += 64) {
        __syncthreads();
#pragma unroll
        for (int l = 0; l < 4; ++l) {
            int idx = t + l * 256;
            int r = idx >> 4, c4 = (idx & 15) << 2;
            *(f4*)&wl[r][c4] = *(const f4*)&Hb[(o0 + r) * C + k0 + c4];
            *(f4*)&xl[r][c4] = *(const f4*)&R[(k0 + r) * C + c0 + c4];
        }
        __syncthreads();
        for (int kk = 0; kk < 64; kk += 4) {
            f4 a[4], bb[4];
#pragma unroll
            for (int i = 0; i < 4; ++i) a[i] = *(const f4*)&wl[ty + 16 * i][kk];
#pragma unroll
            for (int q = 0; q < 4; ++q) bb[q] = *(const f4*)&xl[kk + q][tx * 4];
#pragma unroll
            for (int q = 0; q < 4; ++q) {
                float sq = sl[k0 + kk + q], wq = wtl[k0 + kk + q];
#pragma unroll
                for (int i = 0; i < 4; ++i) {
                    hwacc[i] += a[i][q] * wq;
#pragma unroll
                    for (int j = 0; j < 4; ++j)
                        acc[i][j] += a[i][q] * bb[q][j];
                }
#pragma unroll
                for (int j = 0; j < 4; ++j) qacc[j] += sq * bb[q][j];
            }
        }
    }
    float tj[4], qj[4];
#pragma unroll
    for (int j = 0; j < 4; ++j) {
        tj[j] = tg[c0 + tx * 4 + j];
        qj[j] = INVN * qacc[j] + tj[j];
    }
    short* Wb = W5bf + (size_t)b * C * C;
#pragma unroll
    for (int i = 0; i < 4; ++i) {
        int o = o0 + ty + 16 * i;
        float pi = p[o];
        float lsi = Ls[b * C + o];
#pragma unroll
        for (int j = 0; j < 4; ++j) {
            float w5v = INVN * acc[i][j] + pi * qj[j] + INVN * lsi * tj[j];
            Wb[o * C + c0 + tx * 4 + j] = f2bf(w5v);
        }
    }
    if (jt == 0 && tx == 0) {
        float swtb = swt[b];
        float cpt = consts[0];
#pragma unroll
        for (int i = 0; i < 4; ++i) {
            int o = o0 + ty + 16 * i;
            float inv_o = gamma[o] * rsqrtf(var[o] + BN_EPS_F);
            float pi = p[o];
            bias5[b * C + o] = INVN * hwacc[i] + INVN * swtb * pi
                             + cpt * (INVN * Ls[b * C + o] + pi)
                             + inv_o * brec[o] + beta[o] - mean[o] * inv_o;
        }
    }
}

// ---- final: out = W5 x + bias5 + x (bf16 MFMA, fp32 residual) ----
__global__ __launch_bounds__(256) void final_mfma(const float* __restrict__ x,
                                                  const short* __restrict__ W5bf,
                                                  const short* __restrict__ xT,
                                                  const float* __restrict__ bias5,
                                                  float* __restrict__ out) {
    int b = blockIdx.y;
    int n0 = blockIdx.x * 64;
    int tid = threadIdx.x, lane = tid & 63, wid = tid >> 6;
    int obase = wid * 64;
    int lm = lane & 15, lk = (lane >> 4) * 8;
    const short* A0 = W5bf + ((size_t)(b * C) + obase + lm) * C + lk;
    const short* B0 = xT + ((size_t)b * NPIX + n0 + lm) * C + lk;
    f32x4 acc[4][4] = {};
#pragma unroll
    for (int k = 0; k < C; k += 32) {
        short8 a[4], bv[4];
#pragma unroll
        for (int mi = 0; mi < 4; ++mi) a[mi] = *(const short8*)(A0 + mi * 16 * C + k);
#pragma unroll
        for (int nj = 0; nj < 4; ++nj) bv[nj] = *(const short8*)(B0 + nj * 16 * C + k);
#pragma unroll
        for (int mi = 0; mi < 4; ++mi)
#pragma unroll
            for (int nj = 0; nj < 4; ++nj)
                acc[mi][nj] = __builtin_amdgcn_mfma_f32_16x16x32_bf16(a[mi], bv[nj], acc[mi][nj], 0, 0, 0);
    }
    int r0 = (lane >> 4) * 4;
#pragma unroll
    for (int mi = 0; mi < 4; ++mi) {
#pragma unroll
        for (int r = 0; r < 4; ++r) {
            int o = obase + mi * 16 + r0 + r;
            float bias = bias5[b * C + o];
            const float* xrow = x + ((size_t)(b * C + o)) * NPIX;
            float* orow = out + ((size_t)(b * C + o)) * NPIX;
#pragma unroll
            for (int nj = 0; nj < 4; ++nj) {
                int n = n0 + nj * 16 + lm;
                orow[n] = acc[mi][nj][r] + bias + xrow[n];
            }
        }
    }
}

extern "C" void kernel_launch(void* const* d_in, const int* in_sizes, int n_in,
                              void* d_out, int out_size, void* d_ws, size_t ws_size,
                              hipStream_t stream) {
    const float* x       = (const float*)d_in[0];
    const float* w_theta = (const float*)d_in[1];
    const float* b_theta = (const float*)d_in[2];
    const float* w_phi   = (const float*)d_in[3];
    const float* b_phi   = (const float*)d_in[4];
    const float* w_g     = (const float*)d_in[5];
    const float* b_g     = (const float*)d_in[6];
    const float* w_rec   = (const float*)d_in[7];
    const float* b_rec   = (const float*)d_in[8];
    const float* gamma   = (const float*)d_in[9];
    const float* beta    = (const float*)d_in[10];
    const float* mean    = (const float*)d_in[11];
    const float* var     = (const float*)d_in[12];
    float* out = (float*)d_out;

    // d_out scratch (consumed before final_mfma overwrites everything):
    float* Gp = out;                   // 7*4*256*256 = 1,835,008 f32
    float* H  = out + 1835008;         // 4*256*256 = 262,144 (ends 2,097,152 < 3,211,264)

    char* wsb = (char*)d_ws;
    float* s      = (float*)(wsb + 0);        // 1024 f32 (4 KB)
    float* swt    = (float*)(wsb + 4096);     // 4 f32
    float* consts = (float*)(wsb + 4160);     // 1 f32
    float* p      = (float*)(wsb + 8192);     // 256
    float* tg     = (float*)(wsb + 12288);    // 256
    float* wt     = (float*)(wsb + 16384);    // 256
    float* Ls     = (float*)(wsb + 20480);    // 1024
    float* bias5  = (float*)(wsb + 24576);    // 1024
    float* L      = (float*)(wsb + 32768);    // 256 KB
    float* R      = (float*)(wsb + 294912);   // 256 KB
    short* W5bf   = (short*)(wsb + 557056);   // 512 KB
    short* xbf    = (short*)(wsb + (2u << 20));   // 6.42 MB
    short* xT     = (short*)(wsb + (16u << 20));  // 6.42 MB

    hipMemsetAsync(s, 0, B * C * sizeof(float), stream);
    prep_kernel<<<dim3(NPIX / 64, C / 64, B), dim3(256), 0, stream>>>(x, xbf, xT, s);
    lr_kernel<<<dim3(33), dim3(256), 0, stream>>>(w_rec, w_g, w_phi, w_theta,
                                                  gamma, var, b_g, b_phi, b_theta,
                                                  s, L, R, p, tg, wt, swt, consts);
    xxt_mfma<<<dim3(2, 2, B * KS), dim3(256), 0, stream>>>(xbf, Gp);
    h_kernel<<<dim3(4, 4, B), dim3(256), 0, stream>>>(L, Gp, s, H, Ls);
    w5_kernel<<<dim3(4, 4, B), dim3(256), 0, stream>>>(H, R, s, wt, tg, p, Ls, swt, consts,
                                                       gamma, var, beta, mean, b_rec,
                                                       W5bf, bias5);
    final_mfma<<<dim3(NPIX / 64, B), dim3(256), 0, stream>>>(x, W5bf, xT, bias5, out);
}

// Round 4
// 171.577 us; speedup vs baseline: 1.0243x; 1.0243x over previous
//
#include <hip/hip_runtime.h>

#define B 4
#define C 256
#define CI 128
#define NPIX 3136      // 56*56 = 49 * 64
#define KS 7           // split-K for xxt: 7 chunks of 448
#define BN_EPS_F 1e-5f
#define INVN (1.0f / 3136.0f)

typedef float f4 __attribute__((ext_vector_type(4)));
typedef float f32x4 __attribute__((ext_vector_type(4)));
typedef short short8 __attribute__((ext_vector_type(8)));
typedef short short4v __attribute__((ext_vector_type(4)));

__device__ inline short f2bf(float f) {
    unsigned u = __builtin_bit_cast(unsigned, f);
    unsigned r = (u + 0x7FFFu + ((u >> 16) & 1u)) >> 16;
    return (short)r;
}

// ---- wprep: weights-only precompute + zero s.
//   blocks 0-15:  L = diag(inv) wrec Wg   (256x256)
//   blocks 16-31: R = Wphi^T Wtheta        (256x256)
//   block 32: p = inv.*(wrec bg), tg = Wtheta^T bphi, wt = Wphi^T btheta,
//             consts[0] = bphi.btheta, s[0:1024) = 0
__global__ __launch_bounds__(256) void wprep_kernel(const float* __restrict__ wrec,
                                                    const float* __restrict__ wg,
                                                    const float* __restrict__ wphi,
                                                    const float* __restrict__ wtheta,
                                                    const float* __restrict__ gamma,
                                                    const float* __restrict__ var,
                                                    const float* __restrict__ bg,
                                                    const float* __restrict__ bphi,
                                                    const float* __restrict__ btheta,
                                                    float* __restrict__ L,
                                                    float* __restrict__ R,
                                                    float* __restrict__ p,
                                                    float* __restrict__ tg,
                                                    float* __restrict__ wt,
                                                    float* __restrict__ consts,
                                                    float* __restrict__ s) {
    __shared__ float wl[64][68];
    __shared__ float xl[64][68];
    __shared__ float red[4];
    int bx = blockIdx.x;
    int t = threadIdx.x;
    if (bx == 32) {
        f4 z = {0.f, 0.f, 0.f, 0.f};
        *(f4*)&s[t * 4] = z;                      // zero s[B*C=1024]
        float acc_t = 0.f, acc_w = 0.f;
        for (int j = 0; j < CI; ++j) {            // coalesced across t; 128 iters, TLP+ILP
            acc_t += wtheta[j * C + t] * bphi[j];
            acc_w += wphi[j * C + t] * btheta[j];
        }
        float accp = 0.f;
#pragma unroll
        for (int j4 = 0; j4 < CI; j4 += 4) {      // per-thread contiguous f4 row reads
            f4 w = *(const f4*)&wrec[t * CI + j4];
            f4 b4 = *(const f4*)&bg[j4];
            accp += w[0] * b4[0] + w[1] * b4[1] + w[2] * b4[2] + w[3] * b4[3];
        }
        tg[t] = acc_t;
        wt[t] = acc_w;
        p[t] = gamma[t] * rsqrtf(var[t] + BN_EPS_F) * accp;
        // consts[0] = bphi . btheta  — lane-parallel + shfl reduce (no serial tail)
        float cp = (t < CI) ? bphi[t] * btheta[t] : 0.f;
#pragma unroll
        for (int m = 32; m >= 1; m >>= 1) cp += __shfl_xor(cp, m, 64);
        if ((t & 63) == 0) red[t >> 6] = cp;
        __syncthreads();
        if (t == 0) consts[0] = red[0] + red[1] + red[2] + red[3];
        return;
    }
    bool isL = bx < 16;
    int bi = isL ? bx : bx - 16;
    int r0 = (bi >> 2) * 64, cc0 = (bi & 3) * 64;
    int tx = t & 15, ty = t >> 4;
    float acc[4][4] = {};
    for (int k0 = 0; k0 < CI; k0 += 64) {
        __syncthreads();
        if (isL) {
#pragma unroll
            for (int l = 0; l < 4; ++l) {
                int idx = t + l * 256;
                int r = idx >> 4, c4 = (idx & 15) << 2;
                *(f4*)&wl[r][c4] = *(const f4*)&wrec[(r0 + r) * CI + k0 + c4];
                *(f4*)&xl[r][c4] = *(const f4*)&wg[(size_t)(k0 + r) * C + cc0 + c4];
            }
        } else {
#pragma unroll
            for (int l = 0; l < 4; ++l) {
                int idx = t + l * 256;
                int jl = idx >> 4, cf4 = (idx & 15) << 2;
                f4 v = *(const f4*)&wphi[(size_t)(k0 + jl) * C + r0 + cf4];
#pragma unroll
                for (int i = 0; i < 4; ++i) wl[cf4 + i][jl] = v[i];
                *(f4*)&xl[jl][cf4] = *(const f4*)&wtheta[(size_t)(k0 + jl) * C + cc0 + cf4];
            }
        }
        __syncthreads();
        for (int kk = 0; kk < 64; kk += 4) {
            f4 a[4], bb[4];
#pragma unroll
            for (int i = 0; i < 4; ++i) a[i] = *(const f4*)&wl[ty + 16 * i][kk];
#pragma unroll
            for (int q = 0; q < 4; ++q) bb[q] = *(const f4*)&xl[kk + q][tx * 4];
#pragma unroll
            for (int q = 0; q < 4; ++q)
#pragma unroll
                for (int i = 0; i < 4; ++i)
#pragma unroll
                    for (int j = 0; j < 4; ++j)
                        acc[i][j] += a[i][q] * bb[q][j];
        }
    }
#pragma unroll
    for (int i = 0; i < 4; ++i) {
        int r = r0 + ty + 16 * i;
        float scale = isL ? gamma[r] * rsqrtf(var[r] + BN_EPS_F) : 1.0f;
        float* dst = isL ? L : R;
#pragma unroll
        for (int j = 0; j < 4; ++j)
            dst[r * C + cc0 + tx * 4 + j] = scale * acc[i][j];
    }
}

// ---- prep: xbf[b][c][n]=bf16(x), xT[b][n][c]=bf16(x), s[b][c]=rowsum (atomic) ----
__global__ __launch_bounds__(256) void prep_kernel(const float* __restrict__ x,
                                                   short* __restrict__ xbf,
                                                   short* __restrict__ xT,
                                                   float* __restrict__ s) {
    int b = blockIdx.z, c0 = blockIdx.y * 64, n0 = blockIdx.x * 64;
    __shared__ short lds[64][65];   // [n_local][c_local]
    int t = threadIdx.x;
    int nf = (t & 15) * 4;
    int cr = t >> 4;
    float psum[4];
#pragma unroll
    for (int it = 0; it < 4; ++it) {
        int c = cr + 16 * it;
        f4 v = *(const f4*)&x[((size_t)(b * C + c0 + c)) * NPIX + n0 + nf];
        short4v s4;
        float ps = 0.f;
#pragma unroll
        for (int i = 0; i < 4; ++i) { s4[i] = f2bf(v[i]); ps += v[i]; }
        psum[it] = ps;
        *(short4v*)&xbf[((size_t)(b * C + c0 + c)) * NPIX + n0 + nf] = s4;
#pragma unroll
        for (int i = 0; i < 4; ++i) lds[nf + i][c] = s4[i];
    }
#pragma unroll
    for (int it = 0; it < 4; ++it) {
        float ps = psum[it];
#pragma unroll
        for (int m = 8; m >= 1; m >>= 1) ps += __shfl_xor(ps, m, 64);
        if ((t & 15) == 0) atomicAdd(&s[b * C + c0 + cr + 16 * it], ps);
    }
    __syncthreads();
#pragma unroll
    for (int it = 0; it < 4; ++it) {
        int n = cr + 16 * it;
        short4v s4;
#pragma unroll
        for (int i = 0; i < 4; ++i) s4[i] = lds[n][nf + i];
        *(short4v*)&xT[((size_t)b * NPIX + n0 + n) * C + c0 + nf] = s4;
    }
}

// ---- Gpart[ks][b] = x_chunk x_chunk^T (bf16 MFMA) ----
__global__ __launch_bounds__(256) void xxt_mfma(const short* __restrict__ xbf,
                                                float* __restrict__ Gp) {
    int z = blockIdx.z;
    int b = z / KS, ks = z % KS;
    int tid = threadIdx.x, lane = tid & 63, wid = tid >> 6;
    int ibase = blockIdx.y * 128 + (wid >> 1) * 64;
    int jbase = blockIdx.x * 128 + (wid & 1) * 64;
    int lm = lane & 15, lk = (lane >> 4) * 8;
    const short* A0 = xbf + ((size_t)(b * C) + ibase + lm) * NPIX + lk;
    const short* B0 = xbf + ((size_t)(b * C) + jbase + lm) * NPIX + lk;
    f32x4 acc[4][4] = {};
    int kend = ks * 448 + 448;
    for (int k = ks * 448; k < kend; k += 32) {
        short8 a[4], bv[4];
#pragma unroll
        for (int mi = 0; mi < 4; ++mi) a[mi] = *(const short8*)(A0 + (size_t)mi * 16 * NPIX + k);
#pragma unroll
        for (int nj = 0; nj < 4; ++nj) bv[nj] = *(const short8*)(B0 + (size_t)nj * 16 * NPIX + k);
#pragma unroll
        for (int mi = 0; mi < 4; ++mi)
#pragma unroll
            for (int nj = 0; nj < 4; ++nj)
                acc[mi][nj] = __builtin_amdgcn_mfma_f32_16x16x32_bf16(a[mi], bv[nj], acc[mi][nj], 0, 0, 0);
    }
    float* outp = Gp + ((size_t)(ks * B + b)) * C * C;
    int r0 = (lane >> 4) * 4;
#pragma unroll
    for (int mi = 0; mi < 4; ++mi)
#pragma unroll
        for (int r = 0; r < 4; ++r)
#pragma unroll
            for (int nj = 0; nj < 4; ++nj)
                outp[(ibase + mi * 16 + r0 + r) * C + jbase + nj * 16 + lm] = acc[mi][nj][r];
}

// ---- h: H[b] = L * (sum_ks Gp[ks][b]);  Ls[b] = L s[b] (jt==0 blocks) ----
__global__ __launch_bounds__(256) void h_kernel(const float* __restrict__ L,
                                                const float* __restrict__ Gp,
                                                const float* __restrict__ s,
                                                float* __restrict__ H,
                                                float* __restrict__ Ls) {
    int jt = blockIdx.x, it = blockIdx.y, b = blockIdx.z;
    int i0 = it * 64, j0 = jt * 64;
    __shared__ float wl[64][68];
    __shared__ float xl[64][68];
    __shared__ float sl[C];
    int t = threadIdx.x, tx = t & 15, ty = t >> 4;
    sl[t] = s[b * C + t];
    float acc[4][4] = {};
    float lsacc[4] = {};
    for (int k0 = 0; k0 < C; k0 += 64) {
        __syncthreads();
#pragma unroll
        for (int l = 0; l < 4; ++l) {
            int idx = t + l * 256;
            int r = idx >> 4, c4 = (idx & 15) << 2;
            *(f4*)&wl[r][c4] = *(const f4*)&L[(i0 + r) * C + k0 + c4];
            f4 g = *(const f4*)&Gp[(size_t)b * C * C + (k0 + r) * C + j0 + c4];
#pragma unroll
            for (int ks = 1; ks < KS; ++ks)
                g += *(const f4*)&Gp[(size_t)ks * (B * C * C) + (size_t)b * C * C + (k0 + r) * C + j0 + c4];
            *(f4*)&xl[r][c4] = g;
        }
        __syncthreads();
        for (int kk = 0; kk < 64; kk += 4) {
            f4 a[4], bb[4];
#pragma unroll
            for (int i = 0; i < 4; ++i) a[i] = *(const f4*)&wl[ty + 16 * i][kk];
#pragma unroll
            for (int q = 0; q < 4; ++q) bb[q] = *(const f4*)&xl[kk + q][tx * 4];
#pragma unroll
            for (int q = 0; q < 4; ++q) {
#pragma unroll
                for (int i = 0; i < 4; ++i) {
                    lsacc[i] += ((q == 0) ? a[i][0] * sl[k0 + kk] : 0.f);
#pragma unroll
                    for (int j = 0; j < 4; ++j)
                        acc[i][j] += a[i][q] * bb[q][j];
                }
            }
#pragma unroll
            for (int i = 0; i < 4; ++i) {
                lsacc[i] += a[i][1] * sl[k0 + kk + 1] + a[i][2] * sl[k0 + kk + 2] + a[i][3] * sl[k0 + kk + 3];
            }
        }
    }
    float* Hb = H + (size_t)b * C * C;
#pragma unroll
    for (int i = 0; i < 4; ++i)
#pragma unroll
        for (int j = 0; j < 4; ++j)
            Hb[(i0 + ty + 16 * i) * C + j0 + tx * 4 + j] = acc[i][j];
    if (jt == 0 && tx == 0) {
#pragma unroll
        for (int i = 0; i < 4; ++i) Ls[b * C + i0 + ty + 16 * i] = lsacc[i];
    }
}

// ---- w5: W5bf[b] = bf16((1/N) H R + p*((1/N)s^T R + t)^T + (1/N)(Ls) t^T)
//         bias5[b][o] (jt==0): (1/N)H wt + (1/N)(s.wt) p + cpt((1/N)Ls + p) + BN terms
__global__ __launch_bounds__(256) void w5_kernel(const float* __restrict__ H,
                                                 const float* __restrict__ R,
                                                 const float* __restrict__ s,
                                                 const float* __restrict__ wt,
                                                 const float* __restrict__ tg,
                                                 const float* __restrict__ p,
                                                 const float* __restrict__ Ls,
                                                 const float* __restrict__ consts,
                                                 const float* __restrict__ gamma,
                                                 const float* __restrict__ var,
                                                 const float* __restrict__ beta,
                                                 const float* __restrict__ mean,
                                                 const float* __restrict__ brec,
                                                 short* __restrict__ W5bf,
                                                 float* __restrict__ bias5) {
    int jt = blockIdx.x, it = blockIdx.y, b = blockIdx.z;
    int o0 = it * 64, c0 = jt * 64;
    __shared__ float wl[64][68];
    __shared__ float xl[64][68];
    __shared__ float sl[C];
    __shared__ float wtl[C];
    __shared__ float red[4];
    int t = threadIdx.x, tx = t & 15, ty = t >> 4;
    sl[t] = s[b * C + t];
    wtl[t] = wt[t];
    float acc[4][4] = {};
    float qacc[4] = {};
    float hwacc[4] = {};
    const float* Hb = H + (size_t)b * C * C;
    for (int k0 = 0; k0 < C; k0 += 64) {
        __syncthreads();
#pragma unroll
        for (int l = 0; l < 4; ++l) {
            int idx = t + l * 256;
            int r = idx >> 4, c4 = (idx & 15) << 2;
            *(f4*)&wl[r][c4] = *(const f4*)&Hb[(o0 + r) * C + k0 + c4];
            *(f4*)&xl[r][c4] = *(const f4*)&R[(k0 + r) * C + c0 + c4];
        }
        __syncthreads();
        for (int kk = 0; kk < 64; kk += 4) {
            f4 a[4], bb[4];
#pragma unroll
            for (int i = 0; i < 4; ++i) a[i] = *(const f4*)&wl[ty + 16 * i][kk];
#pragma unroll
            for (int q = 0; q < 4; ++q) bb[q] = *(const f4*)&xl[kk + q][tx * 4];
#pragma unroll
            for (int q = 0; q < 4; ++q) {
                float sq = sl[k0 + kk + q], wq = wtl[k0 + kk + q];
#pragma unroll
                for (int i = 0; i < 4; ++i) {
                    hwacc[i] += a[i][q] * wq;
#pragma unroll
                    for (int j = 0; j < 4; ++j)
                        acc[i][j] += a[i][q] * bb[q][j];
                }
#pragma unroll
                for (int j = 0; j < 4; ++j) qacc[j] += sq * bb[q][j];
            }
        }
    }
    float tj[4], qj[4];
#pragma unroll
    for (int j = 0; j < 4; ++j) {
        tj[j] = tg[c0 + tx * 4 + j];
        qj[j] = INVN * qacc[j] + tj[j];
    }
    short* Wb = W5bf + (size_t)b * C * C;
#pragma unroll
    for (int i = 0; i < 4; ++i) {
        int o = o0 + ty + 16 * i;
        float pi = p[o];
        float lsi = Ls[b * C + o];
#pragma unroll
        for (int j = 0; j < 4; ++j) {
            float w5v = INVN * acc[i][j] + pi * qj[j] + INVN * lsi * tj[j];
            Wb[o * C + c0 + tx * 4 + j] = f2bf(w5v);
        }
    }
    if (jt == 0) {
        // swt = s . wt via block reduction from LDS (values still intact)
        float part = sl[t] * wtl[t];
#pragma unroll
        for (int m = 32; m >= 1; m >>= 1) part += __shfl_xor(part, m, 64);
        if ((t & 63) == 0) red[t >> 6] = part;
        __syncthreads();
        if (tx == 0) {
            float swtb = red[0] + red[1] + red[2] + red[3];
            float cpt = consts[0];
#pragma unroll
            for (int i = 0; i < 4; ++i) {
                int o = o0 + ty + 16 * i;
                float inv_o = gamma[o] * rsqrtf(var[o] + BN_EPS_F);
                float pi = p[o];
                bias5[b * C + o] = INVN * hwacc[i] + INVN * swtb * pi
                                 + cpt * (INVN * Ls[b * C + o] + pi)
                                 + inv_o * brec[o] + beta[o] - mean[o] * inv_o;
            }
        }
    }
}

// ---- final: out = W5 x + bias5 + x (bf16 MFMA, fp32 residual) ----
__global__ __launch_bounds__(256) void final_mfma(const float* __restrict__ x,
                                                  const short* __restrict__ W5bf,
                                                  const short* __restrict__ xT,
                                                  const float* __restrict__ bias5,
                                                  float* __restrict__ out) {
    int b = blockIdx.y;
    int n0 = blockIdx.x * 64;
    int tid = threadIdx.x, lane = tid & 63, wid = tid >> 6;
    int obase = wid * 64;
    int lm = lane & 15, lk = (lane >> 4) * 8;
    const short* A0 = W5bf + ((size_t)(b * C) + obase + lm) * C + lk;
    const short* B0 = xT + ((size_t)b * NPIX + n0 + lm) * C + lk;
    f32x4 acc[4][4] = {};
#pragma unroll
    for (int k = 0; k < C; k += 32) {
        short8 a[4], bv[4];
#pragma unroll
        for (int mi = 0; mi < 4; ++mi) a[mi] = *(const short8*)(A0 + mi * 16 * C + k);
#pragma unroll
        for (int nj = 0; nj < 4; ++nj) bv[nj] = *(const short8*)(B0 + nj * 16 * C + k);
#pragma unroll
        for (int mi = 0; mi < 4; ++mi)
#pragma unroll
            for (int nj = 0; nj < 4; ++nj)
                acc[mi][nj] = __builtin_amdgcn_mfma_f32_16x16x32_bf16(a[mi], bv[nj], acc[mi][nj], 0, 0, 0);
    }
    int r0 = (lane >> 4) * 4;
#pragma unroll
    for (int mi = 0; mi < 4; ++mi) {
#pragma unroll
        for (int r = 0; r < 4; ++r) {
            int o = obase + mi * 16 + r0 + r;
            float bias = bias5[b * C + o];
            const float* xrow = x + ((size_t)(b * C + o)) * NPIX;
            float* orow = out + ((size_t)(b * C + o)) * NPIX;
#pragma unroll
            for (int nj = 0; nj < 4; ++nj) {
                int n = n0 + nj * 16 + lm;
                orow[n] = acc[mi][nj][r] + bias + xrow[n];
            }
        }
    }
}

extern "C" void kernel_launch(void* const* d_in, const int* in_sizes, int n_in,
                              void* d_out, int out_size, void* d_ws, size_t ws_size,
                              hipStream_t stream) {
    const float* x       = (const float*)d_in[0];
    const float* w_theta = (const float*)d_in[1];
    const float* b_theta = (const float*)d_in[2];
    const float* w_phi   = (const float*)d_in[3];
    const float* b_phi   = (const float*)d_in[4];
    const float* w_g     = (const float*)d_in[5];
    const float* b_g     = (const float*)d_in[6];
    const float* w_rec   = (const float*)d_in[7];
    const float* b_rec   = (const float*)d_in[8];
    const float* gamma   = (const float*)d_in[9];
    const float* beta    = (const float*)d_in[10];
    const float* mean    = (const float*)d_in[11];
    const float* var     = (const float*)d_in[12];
    float* out = (float*)d_out;

    // d_out scratch (consumed before final_mfma overwrites everything):
    float* Gp = out;                   // 7*4*256*256 = 1,835,008 f32
    float* H  = out + 1835008;         // 4*256*256 = 262,144 (ends 2,097,152 < 3,211,264)

    char* wsb = (char*)d_ws;
    float* s      = (float*)(wsb + 0);        // 1024 f32 (4 KB)
    float* consts = (float*)(wsb + 4096);     // 1 f32
    float* p      = (float*)(wsb + 8192);     // 256
    float* tg     = (float*)(wsb + 12288);    // 256
    float* wt     = (float*)(wsb + 16384);    // 256
    float* Ls     = (float*)(wsb + 20480);    // 1024
    float* bias5  = (float*)(wsb + 24576);    // 1024
    float* L      = (float*)(wsb + 32768);    // 256 KB
    float* R      = (float*)(wsb + 294912);   // 256 KB
    short* W5bf   = (short*)(wsb + 557056);   // 512 KB
    short* xbf    = (short*)(wsb + (2u << 20));   // 6.42 MB
    short* xT     = (short*)(wsb + (16u << 20));  // 6.42 MB

    wprep_kernel<<<dim3(33), dim3(256), 0, stream>>>(w_rec, w_g, w_phi, w_theta,
                                                     gamma, var, b_g, b_phi, b_theta,
                                                     L, R, p, tg, wt, consts, s);
    prep_kernel<<<dim3(NPIX / 64, C / 64, B), dim3(256), 0, stream>>>(x, xbf, xT, s);
    xxt_mfma<<<dim3(2, 2, B * KS), dim3(256), 0, stream>>>(xbf, Gp);
    h_kernel<<<dim3(4, 4, B), dim3(256), 0, stream>>>(L, Gp, s, H, Ls);
    w5_kernel<<<dim3(4, 4, B), dim3(256), 0, stream>>>(H, R, s, wt, tg, p, Ls, consts,
                                                       gamma, var, beta, mean, b_rec,
                                                       W5bf, bias5);
    final_mfma<<<dim3(NPIX / 64, B), dim3(256), 0, stream>>>(x, W5bf, xT, bias5, out);
}

// Round 5
// 136.990 us; speedup vs baseline: 1.2829x; 1.2525x over previous
//
#include <hip/hip_runtime.h>

#define B 4
#define C 256
#define CI 128
#define NPIX 3136      // 56*56 = 49 * 64
#define KS 7           // split-K for xxt: 7 chunks of 448
#define BN_EPS_F 1e-5f
#define INVN (1.0f / 3136.0f)

typedef float f4 __attribute__((ext_vector_type(4)));
typedef float f32x4 __attribute__((ext_vector_type(4)));
typedef short short8 __attribute__((ext_vector_type(8)));
typedef short short4v __attribute__((ext_vector_type(4)));

__device__ inline short f2bf(float f) {
    unsigned u = __builtin_bit_cast(unsigned, f);
    unsigned r = (u + 0x7FFFu + ((u >> 16) & 1u)) >> 16;
    return (short)r;
}

// ---- vec: p = inv.*(wrec bg), tg = Wtheta^T bphi, wt = Wphi^T btheta,
//           consts[0] = bphi.btheta, s[0:1024) = 0.  1 block, 256 threads.
__global__ __launch_bounds__(256) void vec_kernel(const float* __restrict__ wrec,
                                                  const float* __restrict__ wtheta,
                                                  const float* __restrict__ wphi,
                                                  const float* __restrict__ gamma,
                                                  const float* __restrict__ var,
                                                  const float* __restrict__ bg,
                                                  const float* __restrict__ bphi,
                                                  const float* __restrict__ btheta,
                                                  float* __restrict__ p,
                                                  float* __restrict__ tg,
                                                  float* __restrict__ wt,
                                                  float* __restrict__ consts,
                                                  float* __restrict__ s) {
    __shared__ float red[4];
    int t = threadIdx.x;
    f4 z = {0.f, 0.f, 0.f, 0.f};
    *(f4*)&s[t * 4] = z;                       // zero s[B*C = 1024]
    float acc_t = 0.f, acc_w = 0.f;
    for (int j = 0; j < CI; ++j) {             // coalesced across t
        acc_t = fmaf(wtheta[j * C + t], bphi[j], acc_t);
        acc_w = fmaf(wphi[j * C + t], btheta[j], acc_w);
    }
    float accp = 0.f;
#pragma unroll 4
    for (int j4 = 0; j4 < CI; j4 += 4) {       // modest unroll: keep VGPR low
        f4 w = *(const f4*)&wrec[t * CI + j4];
        f4 b4 = *(const f4*)&bg[j4];
        accp += w[0] * b4[0] + w[1] * b4[1] + w[2] * b4[2] + w[3] * b4[3];
    }
    tg[t] = acc_t;
    wt[t] = acc_w;
    p[t] = gamma[t] * rsqrtf(var[t] + BN_EPS_F) * accp;
    float cp = (t < CI) ? bphi[t] * btheta[t] : 0.f;
#pragma unroll
    for (int m = 32; m >= 1; m >>= 1) cp += __shfl_xor(cp, m, 64);
    if ((t & 63) == 0) red[t >> 6] = cp;
    __syncthreads();
    if (t == 0) consts[0] = red[0] + red[1] + red[2] + red[3];
}

// ---- lmat: L = diag(inv) wrec Wg  (256x256, K=128). grid (4,4). ----
__global__ __launch_bounds__(256) void lmat_kernel(const float* __restrict__ wrec,
                                                   const float* __restrict__ wg,
                                                   const float* __restrict__ gamma,
                                                   const float* __restrict__ var,
                                                   float* __restrict__ L) {
    int j0 = blockIdx.x * 64, i0 = blockIdx.y * 64;
    __shared__ float wl[64][68];
    __shared__ float xl[64][68];
    int t = threadIdx.x, tx = t & 15, ty = t >> 4;
    float acc[4][4] = {};
    for (int k0 = 0; k0 < CI; k0 += 64) {
        __syncthreads();
#pragma unroll
        for (int l = 0; l < 4; ++l) {
            int idx = t + l * 256;
            int r = idx >> 4, c4 = (idx & 15) << 2;
            *(f4*)&wl[r][c4] = *(const f4*)&wrec[(i0 + r) * CI + k0 + c4];
            *(f4*)&xl[r][c4] = *(const f4*)&wg[(size_t)(k0 + r) * C + j0 + c4];
        }
        __syncthreads();
        for (int kk = 0; kk < 64; kk += 4) {
            f4 a[4], bb[4];
#pragma unroll
            for (int i = 0; i < 4; ++i) a[i] = *(const f4*)&wl[ty + 16 * i][kk];
#pragma unroll
            for (int q = 0; q < 4; ++q) bb[q] = *(const f4*)&xl[kk + q][tx * 4];
#pragma unroll
            for (int q = 0; q < 4; ++q)
#pragma unroll
                for (int i = 0; i < 4; ++i)
#pragma unroll
                    for (int j = 0; j < 4; ++j)
                        acc[i][j] += a[i][q] * bb[q][j];
        }
    }
#pragma unroll
    for (int i = 0; i < 4; ++i) {
        int r = i0 + ty + 16 * i;
        float scale = gamma[r] * rsqrtf(var[r] + BN_EPS_F);
#pragma unroll
        for (int j = 0; j < 4; ++j)
            L[r * C + j0 + tx * 4 + j] = scale * acc[i][j];
    }
}

// ---- rmat: R = Wphi^T Wtheta  (256x256, K=128). grid (4,4). ----
__global__ __launch_bounds__(256) void rmat_kernel(const float* __restrict__ wphi,
                                                   const float* __restrict__ wtheta,
                                                   float* __restrict__ R) {
    int j0 = blockIdx.x * 64, i0 = blockIdx.y * 64;
    __shared__ float wl[64][68];   // [r_local][k_local] = wphi[k][i0+r]
    __shared__ float xl[64][68];
    int t = threadIdx.x, tx = t & 15, ty = t >> 4;
    float acc[4][4] = {};
    for (int k0 = 0; k0 < CI; k0 += 64) {
        __syncthreads();
#pragma unroll
        for (int l = 0; l < 4; ++l) {
            int idx = t + l * 256;
            int jl = idx >> 4, cf4 = (idx & 15) << 2;
            f4 v = *(const f4*)&wphi[(size_t)(k0 + jl) * C + i0 + cf4];
#pragma unroll
            for (int i = 0; i < 4; ++i) wl[cf4 + i][jl] = v[i];
            *(f4*)&xl[jl][cf4] = *(const f4*)&wtheta[(size_t)(k0 + jl) * C + j0 + cf4];
        }
        __syncthreads();
        for (int kk = 0; kk < 64; kk += 4) {
            f4 a[4], bb[4];
#pragma unroll
            for (int i = 0; i < 4; ++i) a[i] = *(const f4*)&wl[ty + 16 * i][kk];
#pragma unroll
            for (int q = 0; q < 4; ++q) bb[q] = *(const f4*)&xl[kk + q][tx * 4];
#pragma unroll
            for (int q = 0; q < 4; ++q)
#pragma unroll
                for (int i = 0; i < 4; ++i)
#pragma unroll
                    for (int j = 0; j < 4; ++j)
                        acc[i][j] += a[i][q] * bb[q][j];
        }
    }
#pragma unroll
    for (int i = 0; i < 4; ++i)
#pragma unroll
        for (int j = 0; j < 4; ++j)
            R[(i0 + ty + 16 * i) * C + j0 + tx * 4 + j] = acc[i][j];
}

// ---- prep: xbf[b][c][n]=bf16(x), xT[b][n][c]=bf16(x), s[b][c]=rowsum (atomic) ----
__global__ __launch_bounds__(256) void prep_kernel(const float* __restrict__ x,
                                                   short* __restrict__ xbf,
                                                   short* __restrict__ xT,
                                                   float* __restrict__ s) {
    int b = blockIdx.z, c0 = blockIdx.y * 64, n0 = blockIdx.x * 64;
    __shared__ short lds[64][65];   // [n_local][c_local]
    int t = threadIdx.x;
    int nf = (t & 15) * 4;
    int cr = t >> 4;
    float psum[4];
#pragma unroll
    for (int it = 0; it < 4; ++it) {
        int c = cr + 16 * it;
        f4 v = *(const f4*)&x[((size_t)(b * C + c0 + c)) * NPIX + n0 + nf];
        short4v s4;
        float ps = 0.f;
#pragma unroll
        for (int i = 0; i < 4; ++i) { s4[i] = f2bf(v[i]); ps += v[i]; }
        psum[it] = ps;
        *(short4v*)&xbf[((size_t)(b * C + c0 + c)) * NPIX + n0 + nf] = s4;
#pragma unroll
        for (int i = 0; i < 4; ++i) lds[nf + i][c] = s4[i];
    }
#pragma unroll
    for (int it = 0; it < 4; ++it) {
        float ps = psum[it];
#pragma unroll
        for (int m = 8; m >= 1; m >>= 1) ps += __shfl_xor(ps, m, 64);
        if ((t & 15) == 0) atomicAdd(&s[b * C + c0 + cr + 16 * it], ps);
    }
    __syncthreads();
#pragma unroll
    for (int it = 0; it < 4; ++it) {
        int n = cr + 16 * it;
        short4v s4;
#pragma unroll
        for (int i = 0; i < 4; ++i) s4[i] = lds[n][nf + i];
        *(short4v*)&xT[((size_t)b * NPIX + n0 + n) * C + c0 + nf] = s4;
    }
}

// ---- Gpart[ks][b] = x_chunk x_chunk^T (bf16 MFMA) ----
__global__ __launch_bounds__(256) void xxt_mfma(const short* __restrict__ xbf,
                                                float* __restrict__ Gp) {
    int z = blockIdx.z;
    int b = z / KS, ks = z % KS;
    int tid = threadIdx.x, lane = tid & 63, wid = tid >> 6;
    int ibase = blockIdx.y * 128 + (wid >> 1) * 64;
    int jbase = blockIdx.x * 128 + (wid & 1) * 64;
    int lm = lane & 15, lk = (lane >> 4) * 8;
    const short* A0 = xbf + ((size_t)(b * C) + ibase + lm) * NPIX + lk;
    const short* B0 = xbf + ((size_t)(b * C) + jbase + lm) * NPIX + lk;
    f32x4 acc[4][4] = {};
    int kend = ks * 448 + 448;
    for (int k = ks * 448; k < kend; k += 32) {
        short8 a[4], bv[4];
#pragma unroll
        for (int mi = 0; mi < 4; ++mi) a[mi] = *(const short8*)(A0 + (size_t)mi * 16 * NPIX + k);
#pragma unroll
        for (int nj = 0; nj < 4; ++nj) bv[nj] = *(const short8*)(B0 + (size_t)nj * 16 * NPIX + k);
#pragma unroll
        for (int mi = 0; mi < 4; ++mi)
#pragma unroll
            for (int nj = 0; nj < 4; ++nj)
                acc[mi][nj] = __builtin_amdgcn_mfma_f32_16x16x32_bf16(a[mi], bv[nj], acc[mi][nj], 0, 0, 0);
    }
    float* outp = Gp + ((size_t)(ks * B + b)) * C * C;
    int r0 = (lane >> 4) * 4;
#pragma unroll
    for (int mi = 0; mi < 4; ++mi)
#pragma unroll
        for (int r = 0; r < 4; ++r)
#pragma unroll
            for (int nj = 0; nj < 4; ++nj)
                outp[(ibase + mi * 16 + r0 + r) * C + jbase + nj * 16 + lm] = acc[mi][nj][r];
}

// ---- h: H[b] = L * (sum_ks Gp[ks][b]);  Ls[b] = L s[b] (jt==0 blocks) ----
__global__ __launch_bounds__(256) void h_kernel(const float* __restrict__ L,
                                                const float* __restrict__ Gp,
                                                const float* __restrict__ s,
                                                float* __restrict__ H,
                                                float* __restrict__ Ls) {
    int jt = blockIdx.x, it = blockIdx.y, b = blockIdx.z;
    int i0 = it * 64, j0 = jt * 64;
    __shared__ float wl[64][68];
    __shared__ float xl[64][68];
    __shared__ float sl[C];
    int t = threadIdx.x, tx = t & 15, ty = t >> 4;
    sl[t] = s[b * C + t];
    float acc[4][4] = {};
    float lsacc[4] = {};
    for (int k0 = 0; k0 < C; k0 += 64) {
        __syncthreads();
#pragma unroll
        for (int l = 0; l < 4; ++l) {
            int idx = t + l * 256;
            int r = idx >> 4, c4 = (idx & 15) << 2;
            *(f4*)&wl[r][c4] = *(const f4*)&L[(i0 + r) * C + k0 + c4];
            f4 g = *(const f4*)&Gp[(size_t)b * C * C + (k0 + r) * C + j0 + c4];
#pragma unroll
            for (int ks = 1; ks < KS; ++ks)
                g += *(const f4*)&Gp[(size_t)ks * (B * C * C) + (size_t)b * C * C + (k0 + r) * C + j0 + c4];
            *(f4*)&xl[r][c4] = g;
        }
        __syncthreads();
        for (int kk = 0; kk < 64; kk += 4) {
            f4 a[4], bb[4];
#pragma unroll
            for (int i = 0; i < 4; ++i) a[i] = *(const f4*)&wl[ty + 16 * i][kk];
#pragma unroll
            for (int q = 0; q < 4; ++q) bb[q] = *(const f4*)&xl[kk + q][tx * 4];
#pragma unroll
            for (int q = 0; q < 4; ++q) {
#pragma unroll
                for (int i = 0; i < 4; ++i) {
                    lsacc[i] += ((q == 0) ? a[i][0] * sl[k0 + kk] : 0.f);
#pragma unroll
                    for (int j = 0; j < 4; ++j)
                        acc[i][j] += a[i][q] * bb[q][j];
                }
            }
#pragma unroll
            for (int i = 0; i < 4; ++i) {
                lsacc[i] += a[i][1] * sl[k0 + kk + 1] + a[i][2] * sl[k0 + kk + 2] + a[i][3] * sl[k0 + kk + 3];
            }
        }
    }
    float* Hb = H + (size_t)b * C * C;
#pragma unroll
    for (int i = 0; i < 4; ++i)
#pragma unroll
        for (int j = 0; j < 4; ++j)
            Hb[(i0 + ty + 16 * i) * C + j0 + tx * 4 + j] = acc[i][j];
    if (jt == 0 && tx == 0) {
#pragma unroll
        for (int i = 0; i < 4; ++i) Ls[b * C + i0 + ty + 16 * i] = lsacc[i];
    }
}

// ---- w5: W5bf[b] = bf16((1/N) H R + p*((1/N)s^T R + t)^T + (1/N)(Ls) t^T)
//         bias5[b][o] (jt==0): (1/N)H wt + (1/N)(s.wt) p + cpt((1/N)Ls + p) + BN terms
__global__ __launch_bounds__(256) void w5_kernel(const float* __restrict__ H,
                                                 const float* __restrict__ R,
                                                 const float* __restrict__ s,
                                                 const float* __restrict__ wt,
                                                 const float* __restrict__ tg,
                                                 const float* __restrict__ p,
                                                 const float* __restrict__ Ls,
                                                 const float* __restrict__ consts,
                                                 const float* __restrict__ gamma,
                                                 const float* __restrict__ var,
                                                 const float* __restrict__ beta,
                                                 const float* __restrict__ mean,
                                                 const float* __restrict__ brec,
                                                 short* __restrict__ W5bf,
                                                 float* __restrict__ bias5) {
    int jt = blockIdx.x, it = blockIdx.y, b = blockIdx.z;
    int o0 = it * 64, c0 = jt * 64;
    __shared__ float wl[64][68];
    __shared__ float xl[64][68];
    __shared__ float sl[C];
    __shared__ float wtl[C];
    __shared__ float red[4];
    int t = threadIdx.x, tx = t & 15, ty = t >> 4;
    sl[t] = s[b * C + t];
    wtl[t] = wt[t];
    float acc[4][4] = {};
    float qacc[4] = {};
    float hwacc[4] = {};
    const float* Hb = H + (size_t)b * C * C;
    for (int k0 = 0; k0 < C; k0 += 64) {
        __syncthreads();
#pragma unroll
        for (int l = 0; l < 4; ++l) {
            int idx = t + l * 256;
            int r = idx >> 4, c4 = (idx & 15) << 2;
            *(f4*)&wl[r][c4] = *(const f4*)&Hb[(o0 + r) * C + k0 + c4];
            *(f4*)&xl[r][c4] = *(const f4*)&R[(k0 + r) * C + c0 + c4];
        }
        __syncthreads();
        for (int kk = 0; kk < 64; kk += 4) {
            f4 a[4], bb[4];
#pragma unroll
            for (int i = 0; i < 4; ++i) a[i] = *(const f4*)&wl[ty + 16 * i][kk];
#pragma unroll
            for (int q = 0; q < 4; ++q) bb[q] = *(const f4*)&xl[kk + q][tx * 4];
#pragma unroll
            for (int q = 0; q < 4; ++q) {
                float sq = sl[k0 + kk + q], wq = wtl[k0 + kk + q];
#pragma unroll
                for (int i = 0; i < 4; ++i) {
                    hwacc[i] += a[i][q] * wq;
#pragma unroll
                    for (int j = 0; j < 4; ++j)
                        acc[i][j] += a[i][q] * bb[q][j];
                }
#pragma unroll
                for (int j = 0; j < 4; ++j) qacc[j] += sq * bb[q][j];
            }
        }
    }
    float tj[4], qj[4];
#pragma unroll
    for (int j = 0; j < 4; ++j) {
        tj[j] = tg[c0 + tx * 4 + j];
        qj[j] = INVN * qacc[j] + tj[j];
    }
    short* Wb = W5bf + (size_t)b * C * C;
#pragma unroll
    for (int i = 0; i < 4; ++i) {
        int o = o0 + ty + 16 * i;
        float pi = p[o];
        float lsi = Ls[b * C + o];
#pragma unroll
        for (int j = 0; j < 4; ++j) {
            float w5v = INVN * acc[i][j] + pi * qj[j] + INVN * lsi * tj[j];
            Wb[o * C + c0 + tx * 4 + j] = f2bf(w5v);
        }
    }
    if (jt == 0) {
        float part = sl[t] * wtl[t];
#pragma unroll
        for (int m = 32; m >= 1; m >>= 1) part += __shfl_xor(part, m, 64);
        if ((t & 63) == 0) red[t >> 6] = part;
        __syncthreads();
        if (tx == 0) {
            float swtb = red[0] + red[1] + red[2] + red[3];
            float cpt = consts[0];
#pragma unroll
            for (int i = 0; i < 4; ++i) {
                int o = o0 + ty + 16 * i;
                float inv_o = gamma[o] * rsqrtf(var[o] + BN_EPS_F);
                float pi = p[o];
                bias5[b * C + o] = INVN * hwacc[i] + INVN * swtb * pi
                                 + cpt * (INVN * Ls[b * C + o] + pi)
                                 + inv_o * brec[o] + beta[o] - mean[o] * inv_o;
            }
        }
    }
}

// ---- final: out = W5 x + bias5 + x (bf16 MFMA, fp32 residual) ----
__global__ __launch_bounds__(256) void final_mfma(const float* __restrict__ x,
                                                  const short* __restrict__ W5bf,
                                                  const short* __restrict__ xT,
                                                  const float* __restrict__ bias5,
                                                  float* __restrict__ out) {
    int b = blockIdx.y;
    int n0 = blockIdx.x * 64;
    int tid = threadIdx.x, lane = tid & 63, wid = tid >> 6;
    int obase = wid * 64;
    int lm = lane & 15, lk = (lane >> 4) * 8;
    const short* A0 = W5bf + ((size_t)(b * C) + obase + lm) * C + lk;
    const short* B0 = xT + ((size_t)b * NPIX + n0 + lm) * C + lk;
    f32x4 acc[4][4] = {};
#pragma unroll
    for (int k = 0; k < C; k += 32) {
        short8 a[4], bv[4];
#pragma unroll
        for (int mi = 0; mi < 4; ++mi) a[mi] = *(const short8*)(A0 + mi * 16 * C + k);
#pragma unroll
        for (int nj = 0; nj < 4; ++nj) bv[nj] = *(const short8*)(B0 + nj * 16 * C + k);
#pragma unroll
        for (int mi = 0; mi < 4; ++mi)
#pragma unroll
            for (int nj = 0; nj < 4; ++nj)
                acc[mi][nj] = __builtin_amdgcn_mfma_f32_16x16x32_bf16(a[mi], bv[nj], acc[mi][nj], 0, 0, 0);
    }
    int r0 = (lane >> 4) * 4;
#pragma unroll
    for (int mi = 0; mi < 4; ++mi) {
#pragma unroll
        for (int r = 0; r < 4; ++r) {
            int o = obase + mi * 16 + r0 + r;
            float bias = bias5[b * C + o];
            const float* xrow = x + ((size_t)(b * C + o)) * NPIX;
            float* orow = out + ((size_t)(b * C + o)) * NPIX;
#pragma unroll
            for (int nj = 0; nj < 4; ++nj) {
                int n = n0 + nj * 16 + lm;
                orow[n] = acc[mi][nj][r] + bias + xrow[n];
            }
        }
    }
}

extern "C" void kernel_launch(void* const* d_in, const int* in_sizes, int n_in,
                              void* d_out, int out_size, void* d_ws, size_t ws_size,
                              hipStream_t stream) {
    const float* x       = (const float*)d_in[0];
    const float* w_theta = (const float*)d_in[1];
    const float* b_theta = (const float*)d_in[2];
    const float* w_phi   = (const float*)d_in[3];
    const float* b_phi   = (const float*)d_in[4];
    const float* w_g     = (const float*)d_in[5];
    const float* b_g     = (const float*)d_in[6];
    const float* w_rec   = (const float*)d_in[7];
    const float* b_rec   = (const float*)d_in[8];
    const float* gamma   = (const float*)d_in[9];
    const float* beta    = (const float*)d_in[10];
    const float* mean    = (const float*)d_in[11];
    const float* var     = (const float*)d_in[12];
    float* out = (float*)d_out;

    // d_out scratch (consumed before final_mfma overwrites everything):
    float* Gp = out;                   // 7*4*256*256 = 1,835,008 f32
    float* H  = out + 1835008;         // 4*256*256 = 262,144 (ends 2,097,152 < 3,211,264)

    char* wsb = (char*)d_ws;
    float* s      = (float*)(wsb + 0);        // 1024 f32 (4 KB)
    float* consts = (float*)(wsb + 4096);     // 1 f32
    float* p      = (float*)(wsb + 8192);     // 256
    float* tg     = (float*)(wsb + 12288);    // 256
    float* wt     = (float*)(wsb + 16384);    // 256
    float* Ls     = (float*)(wsb + 20480);    // 1024
    float* bias5  = (float*)(wsb + 24576);    // 1024
    float* L      = (float*)(wsb + 32768);    // 256 KB
    float* R      = (float*)(wsb + 294912);   // 256 KB
    short* W5bf   = (short*)(wsb + 557056);   // 512 KB
    short* xbf    = (short*)(wsb + (2u << 20));   // 6.42 MB
    short* xT     = (short*)(wsb + (16u << 20));  // 6.42 MB

    vec_kernel<<<dim3(1), dim3(256), 0, stream>>>(w_rec, w_theta, w_phi, gamma, var,
                                                  b_g, b_phi, b_theta, p, tg, wt, consts, s);
    lmat_kernel<<<dim3(4, 4), dim3(256), 0, stream>>>(w_rec, w_g, gamma, var, L);
    rmat_kernel<<<dim3(4, 4), dim3(256), 0, stream>>>(w_phi, w_theta, R);
    prep_kernel<<<dim3(NPIX / 64, C / 64, B), dim3(256), 0, stream>>>(x, xbf, xT, s);
    xxt_mfma<<<dim3(2, 2, B * KS), dim3(256), 0, stream>>>(xbf, Gp);
    h_kernel<<<dim3(4, 4, B), dim3(256), 0, stream>>>(L, Gp, s, H, Ls);
    w5_kernel<<<dim3(4, 4, B), dim3(256), 0, stream>>>(H, R, s, wt, tg, p, Ls, consts,
                                                       gamma, var, beta, mean, b_rec,
                                                       W5bf, bias5);
    final_mfma<<<dim3(NPIX / 64, B), dim3(256), 0, stream>>>(x, W5bf, xT, bias5, out);
}